// Round 11
// baseline (66.872 us; speedup 1.0000x reference)
//
#include <hip/hip_runtime.h>
#include <math.h>

#define NROWS 8192
#define CDIM 256
#define KDIM 1000
#define KPAD 1024

// fp32 fallback path tile params (round-2 proven kernel)
#define BC 128
#define BK 64
#define BI 8

typedef __attribute__((ext_vector_type(8))) short bf16x8;
typedef __attribute__((ext_vector_type(4))) float f32x4;
typedef _Float16 f16;
typedef __attribute__((ext_vector_type(4))) _Float16 f16x4;

__device__ __forceinline__ unsigned short f2bf(float x) {
  unsigned int u = __float_as_uint(x);
  u += 0x7fffu + ((u >> 16) & 1u);
  return (unsigned short)(u >> 16);
}
__device__ __forceinline__ float bf2f(unsigned short h) {
  return __uint_as_float(((unsigned int)h) << 16);
}

__device__ __forceinline__ void gl16(const void* g, void* l) {
  __builtin_amdgcn_global_load_lds(
      (const __attribute__((address_space(1))) unsigned int*)g,
      (__attribute__((address_space(3))) unsigned int*)l, 16, 0, 0);
}

// ---------------------------------------------------------------------------
// K1 (fused): per-8-row stripe — stats + scale + split + fragment-major write.
// UNCHANGED (verified, ~HBM floor). Also zeroes the reduce counter each call
// (graph-replay safe). Plane contract:
//   A/B plane: off = ((cfg>>3)*256 + istep)*8192 + (cfg&7)*1024 + l*16
//   U   plane: off = ((kt8*256 + istep))*8192 + kf*1024 + l*16   (kt8 in 0..7)
// ---------------------------------------------------------------------------
__global__ __launch_bounds__(256, 4) void prep_kernel(
    const float* __restrict__ p, const float* __restrict__ z,
    const float* __restrict__ t,
    unsigned short* __restrict__ gAhi, unsigned short* __restrict__ gAlo,
    unsigned short* __restrict__ gBhi, unsigned short* __restrict__ gBlo,
    unsigned short* __restrict__ gUhi, unsigned short* __restrict__ gUlo,
    float* __restrict__ diag, unsigned int* __restrict__ counter) {
  __shared__ float tbuf[8 * 1028];            // 32896 B
  __shared__ float st_s[8], uu_s[8], sa_s[8], sb_s[8];
  __shared__ double r_s[8];
  const int tid = threadIdx.x;
  const int w = tid >> 6, lane = tid & 63;
  const int stripe = blockIdx.x;              // 0..1023
  const int istep = stripe >> 2;              // 32-row istep
  const int qtr = stripe & 3;                 // quarter within istep
  const int i0 = stripe * 8;
  if (stripe == 0 && tid == 0) *counter = 0;  // reset last-block counter

  // ---- P1: t -> LDS + per-row entropy/||t|| stats (wave w owns rows 2w,2w+1)
#pragma unroll
  for (int rr = 0; rr < 2; ++rr) {
    const int row = 2 * w + rr;
    const float* trow = t + (size_t)(i0 + row) * KDIM;
    float stt = 0.f, ent = 0.f, zfl = 0.f;
#pragma unroll
    for (int c = 0; c < 4; ++c) {
      const int k4 = c * 64 + lane;           // float4 index; 250 valid per row
      float4 v = make_float4(0.f, 0.f, 0.f, 0.f);
      if (k4 < 250) {
        v = *(const float4*)(trow + k4 * 4);
        const float vv[4] = {v.x, v.y, v.z, v.w};
#pragma unroll
        for (int q = 0; q < 4; ++q) {
          stt += vv[q] * vv[q];
          if (vv[q] > 0.f) ent += vv[q] * logf(vv[q]);
          else zfl = 1.f;                     // ref: NaN row -> entr zeroed
        }
      }
      *(float4*)&tbuf[row * 1028 + k4 * 4] = v;  // cols 1000..1023 zeroed
    }
#pragma unroll
    for (int off = 32; off; off >>= 1) {
      stt += __shfl_xor(stt, off);
      ent += __shfl_xor(ent, off);
      zfl += __shfl_xor(zfl, off);
    }
    if (lane == 0) {
      const float tnorm = sqrtf(stt);
      st_s[row] = 1.f / tnorm;
      uu_s[row] = stt / (tnorm * tnorm);
      const float entr = (zfl > 0.f) ? 0.f : (-ent);
      r_s[row] = 1.0 - (double)entr / log(1000.0);
    }
  }
  __syncthreads();

  // ---- P2: U conversion. 1024 items = kt8(8) x kf(8) x cl(16); 4 per thread.
#pragma unroll
  for (int it = 0; it < 4; ++it) {
    const int item = it * 256 + tid;
    const int kt8 = item >> 7;
    const int kf = (item >> 4) & 7;
    const int cl = item & 15;
    const int kcl = kf * 16 + cl;             // k-col within the 128-k tile
    unsigned int hi[4], lo[4];
#pragma unroll
    for (int q = 0; q < 4; ++q) {
      const int r0 = 2 * q, r1 = r0 + 1;      // local rows
      const float v0 = tbuf[r0 * 1028 + kt8 * 128 + kcl] * st_s[r0];
      const float v1 = tbuf[r1 * 1028 + kt8 * 128 + kcl] * st_s[r1];
      const unsigned short h0 = f2bf(v0), h1 = f2bf(v1);
      hi[q] = (unsigned int)h0 | ((unsigned int)h1 << 16);
      const unsigned short e0 = f2bf(v0 - bf2f(h0));
      const unsigned short e1 = f2bf(v1 - bf2f(h1));
      lo[q] = (unsigned int)e0 | ((unsigned int)e1 << 16);
    }
    const size_t off = ((size_t)(kt8 * 256 + istep)) * 8192
                       + (size_t)kf * 1024 + (size_t)(qtr * 16 + cl) * 16;
    *(uint4*)((char*)gUhi + off) = make_uint4(hi[0], hi[1], hi[2], hi[3]);
    *(uint4*)((char*)gUlo + off) = make_uint4(lo[0], lo[1], lo[2], lo[3]);
  }
  __syncthreads();

  // ---- P3a: p,z -> LDS (reuse tbuf) + norms + p.z + diag
  float* ptile = tbuf;                 // [8][260]
  float* ztile = tbuf + 8 * 260;       // [8][260]
#pragma unroll
  for (int rr = 0; rr < 2; ++rr) {
    const int row = 2 * w + rr;
    const float* prow = p + (size_t)(i0 + row) * CDIM;
    const float* zrow = z + (size_t)(i0 + row) * CDIM;
    const float4 pv = *(const float4*)(prow + lane * 4);   // 64 f4 per row
    const float4 zv = *(const float4*)(zrow + lane * 4);
    *(float4*)&ptile[row * 260 + lane * 4] = pv;
    *(float4*)&ztile[row * 260 + lane * 4] = zv;
    float sp = pv.x * pv.x + pv.y * pv.y + pv.z * pv.z + pv.w * pv.w;
    float sz = zv.x * zv.x + zv.y * zv.y + zv.z * zv.z + zv.w * zv.w;
    float spz = pv.x * zv.x + pv.y * zv.y + pv.z * zv.z + pv.w * zv.w;
#pragma unroll
    for (int off = 32; off; off >>= 1) {
      sp += __shfl_xor(sp, off);
      sz += __shfl_xor(sz, off);
      spz += __shfl_xor(spz, off);
    }
    if (lane == 0) {
      const double r = r_s[row];
      const float pnorm = sqrtf(sp), znorm = sqrtf(sz);
      const float sav = (float)(r / fmax((double)pnorm, 1e-12));
      const float sbv = (float)(r / fmax((double)znorm, 1e-12));
      sa_s[row] = sav; sb_s[row] = sbv;
      diag[i0 + row] = spz * sav * sbv * uu_s[row];
    }
  }
  __syncthreads();

  // ---- P3b: A/B conversion. 256 items = cfg(16) x cl(16); 1 per thread x2.
  {
    const int cfg = tid >> 4;
    const int cl = tid & 15;
    const int crd = cfg * 16 + cl;
#pragma unroll 1
    for (int which = 0; which < 2; ++which) {
      const float* tile = which ? ztile : ptile;
      const float* ss = which ? sb_s : sa_s;
      unsigned short* ghi = which ? gBhi : gAhi;
      unsigned short* glo = which ? gBlo : gAlo;
      unsigned int hi[4], lo[4];
#pragma unroll
      for (int q = 0; q < 4; ++q) {
        const int r0 = 2 * q, r1 = r0 + 1;
        const float v0 = tile[r0 * 260 + crd] * ss[r0];
        const float v1 = tile[r1 * 260 + crd] * ss[r1];
        const unsigned short h0 = f2bf(v0), h1 = f2bf(v1);
        hi[q] = (unsigned int)h0 | ((unsigned int)h1 << 16);
        const unsigned short e0 = f2bf(v0 - bf2f(h0));
        const unsigned short e1 = f2bf(v1 - bf2f(h1));
        lo[q] = (unsigned int)e0 | ((unsigned int)e1 << 16);
      }
      const size_t off = ((size_t)((cfg >> 3) * 256 + istep)) * 8192
                         + (size_t)(cfg & 7) * 1024 + (size_t)(qtr * 16 + cl) * 16;
      *(uint4*)((char*)ghi + off) = make_uint4(hi[0], hi[1], hi[2], hi[3]);
      *(uint4*)((char*)glo + off) = make_uint4(lo[0], lo[1], lo[2], lo[3]);
    }
  }
}

// ---------------------------------------------------------------------------
// K2: MFMA dual GEMM, split-2 bf16 (hi*hi + lo*hi + hi*lo). UNCHANGED (r10).
// 128c x 128k tile, 8 waves, 3-buffer LDS (144 KB), counted vmcnt(6), one
// barrier per step, setprio, XCD-clustering block decode.
// ---------------------------------------------------------------------------
__global__ __launch_bounds__(512, 2) void mfma_gemm_kernel(
    const unsigned short* __restrict__ gAhi, const unsigned short* __restrict__ gAlo,
    const unsigned short* __restrict__ gBhi, const unsigned short* __restrict__ gBlo,
    const unsigned short* __restrict__ gUhi, const unsigned short* __restrict__ gUlo,
    f16* __restrict__ part1, f16* __restrict__ part2, int steps,
    int split, int swz) {
  __shared__ unsigned short lds[3][6][4096];  // 3 bufs x 6 planes x 8KB = 144KB
  const int tid = threadIdx.x;
  const int lane = tid & 63;
  const int wid = tid >> 6;
  const int wr = wid >> 1, wc = wid & 1;
  int ct, kt, zc;
  if (swz) {
    const int L = blockIdx.x;
    const int xcd = L & 7;
    const int slot = L >> 3;
    zc = xcd * (split >> 3) + (slot >> 4);
    const int rr2 = slot & 15;
    ct = rr2 >> 3;
    kt = rr2 & 7;
  } else {
    const int L = blockIdx.x;
    zc = L >> 4;
    ct = (L >> 3) & 1;
    kt = L & 7;
  }
  const int istep0 = zc * steps;

  f32x4 acc1[2][4], acc2[2][4];
#pragma unroll
  for (int c = 0; c < 2; ++c)
#pragma unroll
    for (int k = 0; k < 4; ++k) {
      acc1[c][k] = (f32x4){0.f, 0.f, 0.f, 0.f};
      acc2[c][k] = (f32x4){0.f, 0.f, 0.f, 0.f};
    }

  const char* sA0 = (const char*)gAhi;
  const char* sA1 = (const char*)gAlo;
  const char* sB0 = (const char*)gBhi;
  const char* sB1 = (const char*)gBlo;
  const char* sU0 = (const char*)gUhi;
  const char* sU1 = (const char*)gUlo;

  auto stage = [&](int buf, int s) {
    const size_t ab = ((size_t)(ct * 256 + istep0 + s)) * 8192 + (size_t)tid * 16;
    const size_t ub = ((size_t)(kt * 256 + istep0 + s)) * 8192 + (size_t)tid * 16;
    gl16(sA0 + ab, &lds[buf][0][tid * 8]);
    gl16(sA1 + ab, &lds[buf][1][tid * 8]);
    gl16(sB0 + ab, &lds[buf][2][tid * 8]);
    gl16(sB1 + ab, &lds[buf][3][tid * 8]);
    gl16(sU0 + ub, &lds[buf][4][tid * 8]);
    gl16(sU1 + ub, &lds[buf][5][tid * 8]);
  };

  stage(0, 0);
  if (steps > 1) stage(1, 1);
  for (int s = 0; s < steps; ++s) {
    const int cur = s % 3;
    if (s < steps - 1) {
      asm volatile("s_waitcnt vmcnt(6)" ::: "memory");  // oldest stage done
    } else {
      asm volatile("s_waitcnt vmcnt(0)" ::: "memory");
    }
    __builtin_amdgcn_s_barrier();          // all waves' staging visible
    asm volatile("" ::: "memory");         // pin LDS reads below the barrier
    if (s + 2 < steps) stage((s + 2) % 3, s + 2);

    bf16x8 ah[2], al[2], bh[2], bl[2], uh[4], ul[4];
#pragma unroll
    for (int c = 0; c < 2; ++c) {
      const int cf = wr * 2 + c;
      ah[c] = *(const bf16x8*)&lds[cur][0][(cf * 64 + lane) * 8];
      al[c] = *(const bf16x8*)&lds[cur][1][(cf * 64 + lane) * 8];
      bh[c] = *(const bf16x8*)&lds[cur][2][(cf * 64 + lane) * 8];
      bl[c] = *(const bf16x8*)&lds[cur][3][(cf * 64 + lane) * 8];
    }
#pragma unroll
    for (int k = 0; k < 4; ++k) {
      const int kf = wc * 4 + k;
      uh[k] = *(const bf16x8*)&lds[cur][4][(kf * 64 + lane) * 8];
      ul[k] = *(const bf16x8*)&lds[cur][5][(kf * 64 + lane) * 8];
    }
    __builtin_amdgcn_s_setprio(1);
#pragma unroll
    for (int k = 0; k < 4; ++k)
#pragma unroll
      for (int c = 0; c < 2; ++c) {
        acc1[c][k] = __builtin_amdgcn_mfma_f32_16x16x32_bf16(ah[c], uh[k], acc1[c][k], 0, 0, 0);
        acc1[c][k] = __builtin_amdgcn_mfma_f32_16x16x32_bf16(al[c], uh[k], acc1[c][k], 0, 0, 0);
        acc1[c][k] = __builtin_amdgcn_mfma_f32_16x16x32_bf16(ah[c], ul[k], acc1[c][k], 0, 0, 0);
        acc2[c][k] = __builtin_amdgcn_mfma_f32_16x16x32_bf16(bh[c], uh[k], acc2[c][k], 0, 0, 0);
        acc2[c][k] = __builtin_amdgcn_mfma_f32_16x16x32_bf16(bl[c], uh[k], acc2[c][k], 0, 0, 0);
        acc2[c][k] = __builtin_amdgcn_mfma_f32_16x16x32_bf16(bh[c], ul[k], acc2[c][k], 0, 0, 0);
      }
    __builtin_amdgcn_s_setprio(0);
    // no trailing barrier: 3-buffer rotation makes WAR impossible, and all
    // ds_reads are consumed (lgkmcnt-waited) before the next entry barrier.
  }

  f16* o1 = part1 + (size_t)zc * (CDIM * KPAD);
  f16* o2 = part2 + (size_t)zc * (CDIM * KPAD);
#pragma unroll
  for (int c = 0; c < 2; ++c)
#pragma unroll
    for (int k = 0; k < 4; ++k)
#pragma unroll
      for (int j = 0; j < 4; ++j) {
        const int cg = ct * 128 + (wr * 2 + c) * 16 + (lane >> 4) * 4 + j;
        const int kg = kt * 128 + (wc * 4 + k) * 16 + (lane & 15);
        o1[(size_t)cg * KPAD + kg] = (f16)acc1[c][k][j];
        o2[(size_t)cg * KPAD + kg] = (f16)acc2[c][k][j];
      }
}

// ---------------------------------------------------------------------------
// K3 (merged): fp16-partial combine + fp64 dot + LAST-BLOCK final scalar.
// Deterministic: each bsum slot is written by a fixed block; the last-block
// election order never changes the summed values. Counter zeroed by prep.
// ---------------------------------------------------------------------------
__global__ __launch_bounds__(256) void reduce_h_kernel(
    const f16* __restrict__ part1, const f16* __restrict__ part2,
    double* __restrict__ bsum, int split,
    const float* __restrict__ diag, float* __restrict__ out,
    unsigned int* __restrict__ counter) {
  const int tid = threadIdx.x;
  const size_t base = ((size_t)blockIdx.x * 256 + tid) * 4;
  double m1[4] = {0, 0, 0, 0}, m2[4] = {0, 0, 0, 0};
#pragma unroll 4
  for (int zz = 0; zz < split; ++zz) {
    const f16x4 a = *(const f16x4*)(part1 + (size_t)zz * (CDIM * KPAD) + base);
    const f16x4 b = *(const f16x4*)(part2 + (size_t)zz * (CDIM * KPAD) + base);
#pragma unroll
    for (int e = 0; e < 4; ++e) {
      m1[e] += (double)(float)a[e];
      m2[e] += (double)(float)b[e];
    }
  }
  double s = 0.0;
#pragma unroll
  for (int e = 0; e < 4; ++e) s += m1[e] * m2[e];
  __shared__ double red[256];
  red[tid] = s;
  __syncthreads();
  for (int off = 128; off; off >>= 1) {
    if (tid < off) red[tid] += red[tid + off];
    __syncthreads();
  }
  __shared__ unsigned int lastflag;
  if (tid == 0) {
    bsum[blockIdx.x] = red[0];
    __threadfence();                       // release bsum (device scope)
    lastflag = (atomicAdd(counter, 1u) == (unsigned)(gridDim.x - 1));
  }
  __syncthreads();
  if (lastflag) {
    __threadfence();                       // acquire all bsum writes
    double s2 = bsum[tid];                 // gridDim.x == 256 == blockDim.x
    double d = 0.0;
    for (int i = tid; i < NROWS; i += 256) d += (double)diag[i];
    __syncthreads();
    red[tid] = s2;
    __syncthreads();
    for (int off = 128; off; off >>= 1) {
      if (tid < off) red[tid] += red[tid + off];
      __syncthreads();
    }
    const double s_all = red[0];
    __syncthreads();
    red[tid] = d;
    __syncthreads();
    for (int off = 128; off; off >>= 1) {
      if (tid < off) red[tid] += red[tid + off];
      __syncthreads();
    }
    if (tid == 0) {
      const double s_diag = red[0];
      const double sel_sum = -(s_all - s_diag);
      const double cnt = (double)NROWS * (double)NROWS - (double)NROWS;
      out[0] = (float)(sel_sum / cnt);
    }
  }
}

// ---------------------------------------------------------------------------
// fp32 fallback path (round-2 proven) — only if workspace is too small.
// ---------------------------------------------------------------------------
__global__ __launch_bounds__(256) void rowstats_kernel(
    const float* __restrict__ p, const float* __restrict__ z,
    const float* __restrict__ t,
    float* __restrict__ sa, float* __restrict__ sb,
    float* __restrict__ st, float* __restrict__ diag) {
  const int i = blockIdx.x;
  const int tid = threadIdx.x;
  const float pv = p[(size_t)i * CDIM + tid];
  const float zv = z[(size_t)i * CDIM + tid];
  float sp = pv * pv, sz = zv * zv, spz = pv * zv;
  float stt = 0.f, ent = 0.f, zfl = 0.f;
  const float* trow = t + (size_t)i * KDIM;
  for (int k = tid; k < KDIM; k += 256) {
    const float tv = trow[k];
    stt += tv * tv;
    if (tv > 0.f) ent += tv * logf(tv);
    else zfl = 1.f;
  }
#pragma unroll
  for (int off = 32; off; off >>= 1) {
    sp  += __shfl_down(sp, off);
    sz  += __shfl_down(sz, off);
    spz += __shfl_down(spz, off);
    stt += __shfl_down(stt, off);
    ent += __shfl_down(ent, off);
    zfl += __shfl_down(zfl, off);
  }
  __shared__ float wred[4][6];
  const int wid = tid >> 6, lane = tid & 63;
  if (lane == 0) {
    wred[wid][0] = sp;  wred[wid][1] = sz;  wred[wid][2] = spz;
    wred[wid][3] = stt; wred[wid][4] = ent; wred[wid][5] = zfl;
  }
  __syncthreads();
  if (tid == 0) {
    sp  = wred[0][0] + wred[1][0] + wred[2][0] + wred[3][0];
    sz  = wred[0][1] + wred[1][1] + wred[2][1] + wred[3][1];
    spz = wred[0][2] + wred[1][2] + wred[2][2] + wred[3][2];
    stt = wred[0][3] + wred[1][3] + wred[2][3] + wred[3][3];
    ent = wred[0][4] + wred[1][4] + wred[2][4] + wred[3][4];
    zfl = wred[0][5] + wred[1][5] + wred[2][5] + wred[3][5];
    const float pnorm = sqrtf(sp);
    const float znorm = sqrtf(sz);
    const float tnorm = sqrtf(stt);
    const float entr = (zfl > 0.f) ? 0.f : (-ent);
    const double r = 1.0 - (double)entr / log(1000.0);
    const float sav = (float)(r / fmax((double)pnorm, 1e-12));
    const float sbv = (float)(r / fmax((double)znorm, 1e-12));
    const float stv = 1.f / tnorm;
    const float uu = stt / (tnorm * tnorm);
    sa[i] = sav; sb[i] = sbv; st[i] = stv;
    diag[i] = spz * sav * sbv * uu;
  }
}

__global__ __launch_bounds__(256) void fp32_gemm_kernel(
    const float* __restrict__ p, const float* __restrict__ z,
    const float* __restrict__ t,
    const float* __restrict__ sa, const float* __restrict__ sb,
    const float* __restrict__ st,
    float* __restrict__ part1, float* __restrict__ part2, int ichunk) {
  __shared__ float As[BI][BC];
  __shared__ float Bs[BI][BC];
  __shared__ float Us[BI][BK];
  const int tid = threadIdx.x;
  const int c0 = blockIdx.x * BC;
  const int k0 = blockIdx.y * BK;
  const int i0 = blockIdx.z * ichunk;
  float acc1[8][4] = {{0.f}};
  float acc2[8][4] = {{0.f}};
  const int tc = tid & 15;
  const int tk = tid >> 4;
  const int lrow = tid >> 5;
  const int lcolA = (tid & 31) * 4;
  const int lcolU = (tid & 31) * 2;
  for (int ib = 0; ib < ichunk; ib += BI) {
    const int i = i0 + ib + lrow;
    const float sav = sa[i], sbv = sb[i], stv = st[i];
    const float4 pv = *(const float4*)(p + (size_t)i * CDIM + c0 + lcolA);
    const float4 zv = *(const float4*)(z + (size_t)i * CDIM + c0 + lcolA);
    const int kk = k0 + lcolU;
    const float u0 = (kk     < KDIM) ? t[(size_t)i * KDIM + kk]     * stv : 0.f;
    const float u1 = (kk + 1 < KDIM) ? t[(size_t)i * KDIM + kk + 1] * stv : 0.f;
    __syncthreads();
    *(float4*)&As[lrow][lcolA] = make_float4(pv.x * sav, pv.y * sav, pv.z * sav, pv.w * sav);
    *(float4*)&Bs[lrow][lcolA] = make_float4(zv.x * sbv, zv.y * sbv, zv.z * sbv, zv.w * sbv);
    Us[lrow][lcolU] = u0;
    Us[lrow][lcolU + 1] = u1;
    __syncthreads();
#pragma unroll
    for (int ii = 0; ii < BI; ++ii) {
      const float4 a0 = *(const float4*)&As[ii][tc * 8];
      const float4 a1 = *(const float4*)&As[ii][tc * 8 + 4];
      const float4 b0 = *(const float4*)&Bs[ii][tc * 8];
      const float4 b1 = *(const float4*)&Bs[ii][tc * 8 + 4];
      const float4 u  = *(const float4*)&Us[ii][tk * 4];
      const float a[8] = {a0.x, a0.y, a0.z, a0.w, a1.x, a1.y, a1.z, a1.w};
      const float b[8] = {b0.x, b0.y, b0.z, b0.w, b1.x, b1.y, b1.z, b1.w};
      const float uv[4] = {u.x, u.y, u.z, u.w};
#pragma unroll
      for (int m = 0; m < 8; ++m)
#pragma unroll
        for (int n = 0; n < 4; ++n) {
          acc1[m][n] = fmaf(a[m], uv[n], acc1[m][n]);
          acc2[m][n] = fmaf(b[m], uv[n], acc2[m][n]);
        }
    }
  }
  float* o1 = part1 + (size_t)blockIdx.z * (CDIM * KPAD);
  float* o2 = part2 + (size_t)blockIdx.z * (CDIM * KPAD);
#pragma unroll
  for (int m = 0; m < 8; ++m) {
    const int c = c0 + tc * 8 + m;
    const int k = k0 + tk * 4;
    *(float4*)&o1[(size_t)c * KPAD + k] = *(const float4*)acc1[m];
    *(float4*)&o2[(size_t)c * KPAD + k] = *(const float4*)acc2[m];
  }
}

__global__ __launch_bounds__(256) void reduce_kernel(
    const float* __restrict__ part1, const float* __restrict__ part2,
    double* __restrict__ bsum, int split) {
  const int tid = threadIdx.x;
  double s = 0.0;
  for (int r = 0; r < 4; ++r) {
    const size_t idx = (size_t)blockIdx.x * 1024 + (size_t)r * 256 + tid;
    double m1 = 0.0, m2 = 0.0;
    for (int zz = 0; zz < split; ++zz) {
      m1 += (double)part1[(size_t)zz * (CDIM * KPAD) + idx];
      m2 += (double)part2[(size_t)zz * (CDIM * KPAD) + idx];
    }
    s += m1 * m2;
  }
  __shared__ double red[256];
  red[tid] = s;
  __syncthreads();
  for (int off = 128; off; off >>= 1) {
    if (tid < off) red[tid] += red[tid + off];
    __syncthreads();
  }
  if (tid == 0) bsum[blockIdx.x] = red[0];
}

__global__ __launch_bounds__(256) void final_kernel(
    const double* __restrict__ bsum, const float* __restrict__ diag,
    float* __restrict__ out, int nb) {
  const int tid = threadIdx.x;
  double s = 0.0;
  for (int i = tid; i < nb; i += 256) s += bsum[i];
  double d = 0.0;
  for (int i = tid; i < NROWS; i += 256) d += (double)diag[i];
  __shared__ double red[256];
  red[tid] = s;
  __syncthreads();
  for (int off = 128; off; off >>= 1) {
    if (tid < off) red[tid] += red[tid + off];
    __syncthreads();
  }
  double s_all = red[0];
  __syncthreads();
  red[tid] = d;
  __syncthreads();
  for (int off = 128; off; off >>= 1) {
    if (tid < off) red[tid] += red[tid + off];
    __syncthreads();
  }
  if (tid == 0) {
    const double s_diag = red[0];
    const double sel_sum = -(s_all - s_diag);
    const double cnt = (double)NROWS * (double)NROWS - (double)NROWS;
    out[0] = (float)(sel_sum / cnt);
  }
}

extern "C" void kernel_launch(void* const* d_in, const int* in_sizes, int n_in,
                              void* d_out, int out_size, void* d_ws, size_t ws_size,
                              hipStream_t stream) {
  const float* p = (const float*)d_in[0];
  const float* z = (const float*)d_in[1];
  const float* t = (const float*)d_in[2];
  float* out = (float*)d_out;
  char* ws = (char*)d_ws;

  float* sa = (float*)ws;
  float* sb = sa + NROWS;
  float* st = sb + NROWS;
  float* diag = st + NROWS;
  const size_t statsB = (size_t)4 * NROWS * sizeof(float);  // 128 KiB

  const size_t planeA = (size_t)2 * 256 * 8 * 1024;   // 4 MiB
  const size_t planeU = (size_t)8 * 256 * 8 * 1024;   // 16 MiB
  const size_t chunkH = (size_t)CDIM * KPAD * 2;      // 512 KiB fp16 partial
  const size_t chunkF = (size_t)CDIM * KPAD * 4;      // 1 MiB fp32 partial

  int split = 16;
  while (split > 4 &&
         statsB + 4 * planeA + 2 * planeU + (size_t)split * 2 * chunkH + 8192 > ws_size)
    split >>= 1;
  const bool use_mfma =
      statsB + 4 * planeA + 2 * planeU + (size_t)split * 2 * chunkH + 8192 <= ws_size;

  if (use_mfma) {
    char* base = ws + statsB;
    unsigned short* gAhi = (unsigned short*)(base);
    unsigned short* gAlo = (unsigned short*)(base + planeA);
    unsigned short* gBhi = (unsigned short*)(base + 2 * planeA);
    unsigned short* gBlo = (unsigned short*)(base + 3 * planeA);
    unsigned short* gUhi = (unsigned short*)(base + 4 * planeA);
    unsigned short* gUlo = (unsigned short*)(base + 4 * planeA + planeU);
    f16* part1 = (f16*)(base + 4 * planeA + 2 * planeU);
    f16* part2 = part1 + (size_t)split * (CDIM * KPAD);
    double* bsum = (double*)(part2 + (size_t)split * (CDIM * KPAD));
    unsigned int* counter = (unsigned int*)(bsum + 256);
    const int steps = (NROWS / split) / 32;
    const int nblocks = 16 * split;             // (2 ct x 8 kt) x split
    const int swz = (split % 8 == 0) ? 1 : 0;   // XCD-cluster decode valid

    hipLaunchKernelGGL(prep_kernel, dim3(1024), dim3(256), 0, stream,
                       p, z, t, gAhi, gAlo, gBhi, gBlo, gUhi, gUlo, diag,
                       counter);
    hipLaunchKernelGGL(mfma_gemm_kernel, dim3(nblocks), dim3(512), 0, stream,
                       gAhi, gAlo, gBhi, gBlo, gUhi, gUlo, part1, part2,
                       steps, split, swz);
    hipLaunchKernelGGL(reduce_h_kernel, dim3(256), dim3(256), 0, stream,
                       part1, part2, bsum, split, diag, out, counter);
  } else {
    int osplit = 16;
    while (osplit > 1 &&
           statsB + (size_t)osplit * chunkF * 2 + 8192 > ws_size)
      osplit >>= 1;
    float* part1 = (float*)(ws + statsB);
    float* part2 = part1 + (size_t)osplit * (CDIM * KPAD);
    double* bsum = (double*)(part2 + (size_t)osplit * (CDIM * KPAD));
    hipLaunchKernelGGL(rowstats_kernel, dim3(NROWS), dim3(256), 0, stream,
                       p, z, t, sa, sb, st, diag);
    hipLaunchKernelGGL(fp32_gemm_kernel, dim3(CDIM / BC, KPAD / BK, osplit),
                       dim3(256), 0, stream,
                       p, z, t, sa, sb, st, part1, part2, NROWS / osplit);
    hipLaunchKernelGGL(reduce_kernel, dim3(256), dim3(256), 0, stream,
                       part1, part2, bsum, osplit);
    hipLaunchKernelGGL(final_kernel, dim3(1), dim3(256), 0, stream,
                       bsum, diag, out, 256);
  }
}

// Round 12
// 63.076 us; speedup vs baseline: 1.0602x; 1.0602x over previous
//
#include <hip/hip_runtime.h>
#include <math.h>

#define NROWS 8192
#define CDIM 256
#define KDIM 1000
#define KPAD 1024

// fp32 fallback path tile params (round-2 proven kernel)
#define BC 128
#define BK 64
#define BI 8

typedef __attribute__((ext_vector_type(8))) short bf16x8;
typedef __attribute__((ext_vector_type(4))) float f32x4;
typedef _Float16 f16;
typedef __attribute__((ext_vector_type(4))) _Float16 f16x4;

__device__ __forceinline__ unsigned short f2bf(float x) {
  unsigned int u = __float_as_uint(x);
  u += 0x7fffu + ((u >> 16) & 1u);
  return (unsigned short)(u >> 16);
}
__device__ __forceinline__ float bf2f(unsigned short h) {
  return __uint_as_float(((unsigned int)h) << 16);
}

__device__ __forceinline__ void gl16(const void* g, void* l) {
  __builtin_amdgcn_global_load_lds(
      (const __attribute__((address_space(1))) unsigned int*)g,
      (__attribute__((address_space(3))) unsigned int*)l, 16, 0, 0);
}

// ---------------------------------------------------------------------------
// K1 (fused): per-8-row stripe — stats + scale + split + fragment-major write.
// UNCHANGED (verified, ~HBM floor). Plane contract:
//   A/B plane: off = ((cfg>>3)*256 + istep)*8192 + (cfg&7)*1024 + l*16
//   U   plane: off = ((kt8*256 + istep))*8192 + kf*1024 + l*16   (kt8 in 0..7)
// ---------------------------------------------------------------------------
__global__ __launch_bounds__(256, 4) void prep_kernel(
    const float* __restrict__ p, const float* __restrict__ z,
    const float* __restrict__ t,
    unsigned short* __restrict__ gAhi, unsigned short* __restrict__ gAlo,
    unsigned short* __restrict__ gBhi, unsigned short* __restrict__ gBlo,
    unsigned short* __restrict__ gUhi, unsigned short* __restrict__ gUlo,
    float* __restrict__ diag) {
  __shared__ float tbuf[8 * 1028];            // 32896 B
  __shared__ float st_s[8], uu_s[8], sa_s[8], sb_s[8];
  __shared__ double r_s[8];
  const int tid = threadIdx.x;
  const int w = tid >> 6, lane = tid & 63;
  const int stripe = blockIdx.x;              // 0..1023
  const int istep = stripe >> 2;              // 32-row istep
  const int qtr = stripe & 3;                 // quarter within istep
  const int i0 = stripe * 8;

  // ---- P1: t -> LDS + per-row entropy/||t|| stats (wave w owns rows 2w,2w+1)
#pragma unroll
  for (int rr = 0; rr < 2; ++rr) {
    const int row = 2 * w + rr;
    const float* trow = t + (size_t)(i0 + row) * KDIM;
    float stt = 0.f, ent = 0.f, zfl = 0.f;
#pragma unroll
    for (int c = 0; c < 4; ++c) {
      const int k4 = c * 64 + lane;           // float4 index; 250 valid per row
      float4 v = make_float4(0.f, 0.f, 0.f, 0.f);
      if (k4 < 250) {
        v = *(const float4*)(trow + k4 * 4);
        const float vv[4] = {v.x, v.y, v.z, v.w};
#pragma unroll
        for (int q = 0; q < 4; ++q) {
          stt += vv[q] * vv[q];
          if (vv[q] > 0.f) ent += vv[q] * logf(vv[q]);
          else zfl = 1.f;                     // ref: NaN row -> entr zeroed
        }
      }
      *(float4*)&tbuf[row * 1028 + k4 * 4] = v;  // cols 1000..1023 zeroed
    }
#pragma unroll
    for (int off = 32; off; off >>= 1) {
      stt += __shfl_xor(stt, off);
      ent += __shfl_xor(ent, off);
      zfl += __shfl_xor(zfl, off);
    }
    if (lane == 0) {
      const float tnorm = sqrtf(stt);
      st_s[row] = 1.f / tnorm;
      uu_s[row] = stt / (tnorm * tnorm);
      const float entr = (zfl > 0.f) ? 0.f : (-ent);
      r_s[row] = 1.0 - (double)entr / log(1000.0);
    }
  }
  __syncthreads();

  // ---- P2: U conversion. 1024 items = kt8(8) x kf(8) x cl(16); 4 per thread.
#pragma unroll
  for (int it = 0; it < 4; ++it) {
    const int item = it * 256 + tid;
    const int kt8 = item >> 7;
    const int kf = (item >> 4) & 7;
    const int cl = item & 15;
    const int kcl = kf * 16 + cl;             // k-col within the 128-k tile
    unsigned int hi[4], lo[4];
#pragma unroll
    for (int q = 0; q < 4; ++q) {
      const int r0 = 2 * q, r1 = r0 + 1;      // local rows
      const float v0 = tbuf[r0 * 1028 + kt8 * 128 + kcl] * st_s[r0];
      const float v1 = tbuf[r1 * 1028 + kt8 * 128 + kcl] * st_s[r1];
      const unsigned short h0 = f2bf(v0), h1 = f2bf(v1);
      hi[q] = (unsigned int)h0 | ((unsigned int)h1 << 16);
      const unsigned short e0 = f2bf(v0 - bf2f(h0));
      const unsigned short e1 = f2bf(v1 - bf2f(h1));
      lo[q] = (unsigned int)e0 | ((unsigned int)e1 << 16);
    }
    const size_t off = ((size_t)(kt8 * 256 + istep)) * 8192
                       + (size_t)kf * 1024 + (size_t)(qtr * 16 + cl) * 16;
    *(uint4*)((char*)gUhi + off) = make_uint4(hi[0], hi[1], hi[2], hi[3]);
    *(uint4*)((char*)gUlo + off) = make_uint4(lo[0], lo[1], lo[2], lo[3]);
  }
  __syncthreads();

  // ---- P3a: p,z -> LDS (reuse tbuf) + norms + p.z + diag
  float* ptile = tbuf;                 // [8][260]
  float* ztile = tbuf + 8 * 260;       // [8][260]
#pragma unroll
  for (int rr = 0; rr < 2; ++rr) {
    const int row = 2 * w + rr;
    const float* prow = p + (size_t)(i0 + row) * CDIM;
    const float* zrow = z + (size_t)(i0 + row) * CDIM;
    const float4 pv = *(const float4*)(prow + lane * 4);   // 64 f4 per row
    const float4 zv = *(const float4*)(zrow + lane * 4);
    *(float4*)&ptile[row * 260 + lane * 4] = pv;
    *(float4*)&ztile[row * 260 + lane * 4] = zv;
    float sp = pv.x * pv.x + pv.y * pv.y + pv.z * pv.z + pv.w * pv.w;
    float sz = zv.x * zv.x + zv.y * zv.y + zv.z * zv.z + zv.w * zv.w;
    float spz = pv.x * zv.x + pv.y * zv.y + pv.z * zv.z + pv.w * zv.w;
#pragma unroll
    for (int off = 32; off; off >>= 1) {
      sp += __shfl_xor(sp, off);
      sz += __shfl_xor(sz, off);
      spz += __shfl_xor(spz, off);
    }
    if (lane == 0) {
      const double r = r_s[row];
      const float pnorm = sqrtf(sp), znorm = sqrtf(sz);
      const float sav = (float)(r / fmax((double)pnorm, 1e-12));
      const float sbv = (float)(r / fmax((double)znorm, 1e-12));
      sa_s[row] = sav; sb_s[row] = sbv;
      diag[i0 + row] = spz * sav * sbv * uu_s[row];
    }
  }
  __syncthreads();

  // ---- P3b: A/B conversion. 256 items = cfg(16) x cl(16); 1 per thread x2.
  {
    const int cfg = tid >> 4;
    const int cl = tid & 15;
    const int crd = cfg * 16 + cl;
#pragma unroll 1
    for (int which = 0; which < 2; ++which) {
      const float* tile = which ? ztile : ptile;
      const float* ss = which ? sb_s : sa_s;
      unsigned short* ghi = which ? gBhi : gAhi;
      unsigned short* glo = which ? gBlo : gAlo;
      unsigned int hi[4], lo[4];
#pragma unroll
      for (int q = 0; q < 4; ++q) {
        const int r0 = 2 * q, r1 = r0 + 1;
        const float v0 = tile[r0 * 260 + crd] * ss[r0];
        const float v1 = tile[r1 * 260 + crd] * ss[r1];
        const unsigned short h0 = f2bf(v0), h1 = f2bf(v1);
        hi[q] = (unsigned int)h0 | ((unsigned int)h1 << 16);
        const unsigned short e0 = f2bf(v0 - bf2f(h0));
        const unsigned short e1 = f2bf(v1 - bf2f(h1));
        lo[q] = (unsigned int)e0 | ((unsigned int)e1 << 16);
      }
      const size_t off = ((size_t)((cfg >> 3) * 256 + istep)) * 8192
                         + (size_t)(cfg & 7) * 1024 + (size_t)(qtr * 16 + cl) * 16;
      *(uint4*)((char*)ghi + off) = make_uint4(hi[0], hi[1], hi[2], hi[3]);
      *(uint4*)((char*)glo + off) = make_uint4(lo[0], lo[1], lo[2], lo[3]);
    }
  }
}

// ---------------------------------------------------------------------------
// K2: MFMA dual GEMM, split-2 bf16 (hi*hi + lo*hi + hi*lo).
// r6-proven structure: 128c x 128k tile, 8 waves (4wr x 2wc) of 32c x 64k,
// 3-buffer LDS (144 KB), counted vmcnt(6), one barrier per step, setprio.
// 1-D grid + XCD-clustering decode — the 16 blocks of one zc-group
// (which share a 3 MiB plane slice) land on one XCD so staging reads hit
// that XCD's L2 instead of streaming from L3.
//   L = blockIdx.x; xcd = L&7; slot = L>>3;
//   zc = xcd*(split/8) + slot/16; ct = (slot%16)>>3; kt = slot&7.
// ---------------------------------------------------------------------------
__global__ __launch_bounds__(512, 2) void mfma_gemm_kernel(
    const unsigned short* __restrict__ gAhi, const unsigned short* __restrict__ gAlo,
    const unsigned short* __restrict__ gBhi, const unsigned short* __restrict__ gBlo,
    const unsigned short* __restrict__ gUhi, const unsigned short* __restrict__ gUlo,
    f16* __restrict__ part1, f16* __restrict__ part2, int steps,
    int split, int swz) {
  __shared__ unsigned short lds[3][6][4096];  // 3 bufs x 6 planes x 8KB = 144KB
  const int tid = threadIdx.x;
  const int lane = tid & 63;
  const int wid = tid >> 6;
  const int wr = wid >> 1, wc = wid & 1;
  int ct, kt, zc;
  if (swz) {
    const int L = blockIdx.x;
    const int xcd = L & 7;
    const int slot = L >> 3;
    zc = xcd * (split >> 3) + (slot >> 4);
    const int rr2 = slot & 15;
    ct = rr2 >> 3;
    kt = rr2 & 7;
  } else {
    const int L = blockIdx.x;
    zc = L >> 4;
    ct = (L >> 3) & 1;
    kt = L & 7;
  }
  const int istep0 = zc * steps;

  f32x4 acc1[2][4], acc2[2][4];
#pragma unroll
  for (int c = 0; c < 2; ++c)
#pragma unroll
    for (int k = 0; k < 4; ++k) {
      acc1[c][k] = (f32x4){0.f, 0.f, 0.f, 0.f};
      acc2[c][k] = (f32x4){0.f, 0.f, 0.f, 0.f};
    }

  const char* sA0 = (const char*)gAhi;
  const char* sA1 = (const char*)gAlo;
  const char* sB0 = (const char*)gBhi;
  const char* sB1 = (const char*)gBlo;
  const char* sU0 = (const char*)gUhi;
  const char* sU1 = (const char*)gUlo;

  auto stage = [&](int buf, int s) {
    const size_t ab = ((size_t)(ct * 256 + istep0 + s)) * 8192 + (size_t)tid * 16;
    const size_t ub = ((size_t)(kt * 256 + istep0 + s)) * 8192 + (size_t)tid * 16;
    gl16(sA0 + ab, &lds[buf][0][tid * 8]);
    gl16(sA1 + ab, &lds[buf][1][tid * 8]);
    gl16(sB0 + ab, &lds[buf][2][tid * 8]);
    gl16(sB1 + ab, &lds[buf][3][tid * 8]);
    gl16(sU0 + ub, &lds[buf][4][tid * 8]);
    gl16(sU1 + ub, &lds[buf][5][tid * 8]);
  };

  stage(0, 0);
  if (steps > 1) stage(1, 1);
  for (int s = 0; s < steps; ++s) {
    const int cur = s % 3;
    if (s < steps - 1) {
      asm volatile("s_waitcnt vmcnt(6)" ::: "memory");  // oldest stage done
    } else {
      asm volatile("s_waitcnt vmcnt(0)" ::: "memory");
    }
    __builtin_amdgcn_s_barrier();          // all waves' staging visible
    asm volatile("" ::: "memory");         // pin LDS reads below the barrier
    if (s + 2 < steps) stage((s + 2) % 3, s + 2);

    bf16x8 ah[2], al[2], bh[2], bl[2], uh[4], ul[4];
#pragma unroll
    for (int c = 0; c < 2; ++c) {
      const int cf = wr * 2 + c;
      ah[c] = *(const bf16x8*)&lds[cur][0][(cf * 64 + lane) * 8];
      al[c] = *(const bf16x8*)&lds[cur][1][(cf * 64 + lane) * 8];
      bh[c] = *(const bf16x8*)&lds[cur][2][(cf * 64 + lane) * 8];
      bl[c] = *(const bf16x8*)&lds[cur][3][(cf * 64 + lane) * 8];
    }
#pragma unroll
    for (int k = 0; k < 4; ++k) {
      const int kf = wc * 4 + k;
      uh[k] = *(const bf16x8*)&lds[cur][4][(kf * 64 + lane) * 8];
      ul[k] = *(const bf16x8*)&lds[cur][5][(kf * 64 + lane) * 8];
    }
    __builtin_amdgcn_s_setprio(1);
#pragma unroll
    for (int k = 0; k < 4; ++k)
#pragma unroll
      for (int c = 0; c < 2; ++c) {
        acc1[c][k] = __builtin_amdgcn_mfma_f32_16x16x32_bf16(ah[c], uh[k], acc1[c][k], 0, 0, 0);
        acc1[c][k] = __builtin_amdgcn_mfma_f32_16x16x32_bf16(al[c], uh[k], acc1[c][k], 0, 0, 0);
        acc1[c][k] = __builtin_amdgcn_mfma_f32_16x16x32_bf16(ah[c], ul[k], acc1[c][k], 0, 0, 0);
        acc2[c][k] = __builtin_amdgcn_mfma_f32_16x16x32_bf16(bh[c], uh[k], acc2[c][k], 0, 0, 0);
        acc2[c][k] = __builtin_amdgcn_mfma_f32_16x16x32_bf16(bl[c], uh[k], acc2[c][k], 0, 0, 0);
        acc2[c][k] = __builtin_amdgcn_mfma_f32_16x16x32_bf16(bh[c], ul[k], acc2[c][k], 0, 0, 0);
      }
    __builtin_amdgcn_s_setprio(0);
    // no trailing barrier: 3-buffer rotation makes WAR impossible, and all
    // ds_reads are consumed (lgkmcnt-waited) before the next entry barrier.
  }

  f16* o1 = part1 + (size_t)zc * (CDIM * KPAD);
  f16* o2 = part2 + (size_t)zc * (CDIM * KPAD);
#pragma unroll
  for (int c = 0; c < 2; ++c)
#pragma unroll
    for (int k = 0; k < 4; ++k)
#pragma unroll
      for (int j = 0; j < 4; ++j) {
        const int cg = ct * 128 + (wr * 2 + c) * 16 + (lane >> 4) * 4 + j;
        const int kg = kt * 128 + (wc * 4 + k) * 16 + (lane & 15);
        o1[(size_t)cg * KPAD + kg] = (f16)acc1[c][k][j];
        o2[(size_t)cg * KPAD + kg] = (f16)acc2[c][k][j];
      }
}

// ---------------------------------------------------------------------------
// K3: vectorized fp16-partial combine + fp64 dot (r6/r10-proven).
// ---------------------------------------------------------------------------
__global__ __launch_bounds__(256) void reduce_h_kernel(
    const f16* __restrict__ part1, const f16* __restrict__ part2,
    double* __restrict__ bsum, int split) {
  const int tid = threadIdx.x;
  const size_t base = ((size_t)blockIdx.x * 256 + tid) * 4;
  double m1[4] = {0, 0, 0, 0}, m2[4] = {0, 0, 0, 0};
#pragma unroll 4
  for (int zz = 0; zz < split; ++zz) {
    const f16x4 a = *(const f16x4*)(part1 + (size_t)zz * (CDIM * KPAD) + base);
    const f16x4 b = *(const f16x4*)(part2 + (size_t)zz * (CDIM * KPAD) + base);
#pragma unroll
    for (int e = 0; e < 4; ++e) {
      m1[e] += (double)(float)a[e];
      m2[e] += (double)(float)b[e];
    }
  }
  double s = 0.0;
#pragma unroll
  for (int e = 0; e < 4; ++e) s += m1[e] * m2[e];
  __shared__ double red[256];
  red[tid] = s;
  __syncthreads();
  for (int off = 128; off; off >>= 1) {
    if (tid < off) red[tid] += red[tid + off];
    __syncthreads();
  }
  if (tid == 0) bsum[blockIdx.x] = red[0];
}

// ---------------------------------------------------------------------------
// fp32 fallback path (round-2 proven) — only if workspace is too small.
// ---------------------------------------------------------------------------
__global__ __launch_bounds__(256) void rowstats_kernel(
    const float* __restrict__ p, const float* __restrict__ z,
    const float* __restrict__ t,
    float* __restrict__ sa, float* __restrict__ sb,
    float* __restrict__ st, float* __restrict__ diag) {
  const int i = blockIdx.x;
  const int tid = threadIdx.x;
  const float pv = p[(size_t)i * CDIM + tid];
  const float zv = z[(size_t)i * CDIM + tid];
  float sp = pv * pv, sz = zv * zv, spz = pv * zv;
  float stt = 0.f, ent = 0.f, zfl = 0.f;
  const float* trow = t + (size_t)i * KDIM;
  for (int k = tid; k < KDIM; k += 256) {
    const float tv = trow[k];
    stt += tv * tv;
    if (tv > 0.f) ent += tv * logf(tv);
    else zfl = 1.f;
  }
#pragma unroll
  for (int off = 32; off; off >>= 1) {
    sp  += __shfl_down(sp, off);
    sz  += __shfl_down(sz, off);
    spz += __shfl_down(spz, off);
    stt += __shfl_down(stt, off);
    ent += __shfl_down(ent, off);
    zfl += __shfl_down(zfl, off);
  }
  __shared__ float wred[4][6];
  const int wid = tid >> 6, lane = tid & 63;
  if (lane == 0) {
    wred[wid][0] = sp;  wred[wid][1] = sz;  wred[wid][2] = spz;
    wred[wid][3] = stt; wred[wid][4] = ent; wred[wid][5] = zfl;
  }
  __syncthreads();
  if (tid == 0) {
    sp  = wred[0][0] + wred[1][0] + wred[2][0] + wred[3][0];
    sz  = wred[0][1] + wred[1][1] + wred[2][1] + wred[3][1];
    spz = wred[0][2] + wred[1][2] + wred[2][2] + wred[3][2];
    stt = wred[0][3] + wred[1][3] + wred[2][3] + wred[3][3];
    ent = wred[0][4] + wred[1][4] + wred[2][4] + wred[3][4];
    zfl = wred[0][5] + wred[1][5] + wred[2][5] + wred[3][5];
    const float pnorm = sqrtf(sp);
    const float znorm = sqrtf(sz);
    const float tnorm = sqrtf(stt);
    const float entr = (zfl > 0.f) ? 0.f : (-ent);
    const double r = 1.0 - (double)entr / log(1000.0);
    const float sav = (float)(r / fmax((double)pnorm, 1e-12));
    const float sbv = (float)(r / fmax((double)znorm, 1e-12));
    const float stv = 1.f / tnorm;
    const float uu = stt / (tnorm * tnorm);
    sa[i] = sav; sb[i] = sbv; st[i] = stv;
    diag[i] = spz * sav * sbv * uu;
  }
}

__global__ __launch_bounds__(256) void fp32_gemm_kernel(
    const float* __restrict__ p, const float* __restrict__ z,
    const float* __restrict__ t,
    const float* __restrict__ sa, const float* __restrict__ sb,
    const float* __restrict__ st,
    float* __restrict__ part1, float* __restrict__ part2, int ichunk) {
  __shared__ float As[BI][BC];
  __shared__ float Bs[BI][BC];
  __shared__ float Us[BI][BK];
  const int tid = threadIdx.x;
  const int c0 = blockIdx.x * BC;
  const int k0 = blockIdx.y * BK;
  const int i0 = blockIdx.z * ichunk;
  float acc1[8][4] = {{0.f}};
  float acc2[8][4] = {{0.f}};
  const int tc = tid & 15;
  const int tk = tid >> 4;
  const int lrow = tid >> 5;
  const int lcolA = (tid & 31) * 4;
  const int lcolU = (tid & 31) * 2;
  for (int ib = 0; ib < ichunk; ib += BI) {
    const int i = i0 + ib + lrow;
    const float sav = sa[i], sbv = sb[i], stv = st[i];
    const float4 pv = *(const float4*)(p + (size_t)i * CDIM + c0 + lcolA);
    const float4 zv = *(const float4*)(z + (size_t)i * CDIM + c0 + lcolA);
    const int kk = k0 + lcolU;
    const float u0 = (kk     < KDIM) ? t[(size_t)i * KDIM + kk]     * stv : 0.f;
    const float u1 = (kk + 1 < KDIM) ? t[(size_t)i * KDIM + kk + 1] * stv : 0.f;
    __syncthreads();
    *(float4*)&As[lrow][lcolA] = make_float4(pv.x * sav, pv.y * sav, pv.z * sav, pv.w * sav);
    *(float4*)&Bs[lrow][lcolA] = make_float4(zv.x * sbv, zv.y * sbv, zv.z * sbv, zv.w * sbv);
    Us[lrow][lcolU] = u0;
    Us[lrow][lcolU + 1] = u1;
    __syncthreads();
#pragma unroll
    for (int ii = 0; ii < BI; ++ii) {
      const float4 a0 = *(const float4*)&As[ii][tc * 8];
      const float4 a1 = *(const float4*)&As[ii][tc * 8 + 4];
      const float4 b0 = *(const float4*)&Bs[ii][tc * 8];
      const float4 b1 = *(const float4*)&Bs[ii][tc * 8 + 4];
      const float4 u  = *(const float4*)&Us[ii][tk * 4];
      const float a[8] = {a0.x, a0.y, a0.z, a0.w, a1.x, a1.y, a1.z, a1.w};
      const float b[8] = {b0.x, b0.y, b0.z, b0.w, b1.x, b1.y, b1.z, b1.w};
      const float uv[4] = {u.x, u.y, u.z, u.w};
#pragma unroll
      for (int m = 0; m < 8; ++m)
#pragma unroll
        for (int n = 0; n < 4; ++n) {
          acc1[m][n] = fmaf(a[m], uv[n], acc1[m][n]);
          acc2[m][n] = fmaf(b[m], uv[n], acc2[m][n]);
        }
    }
  }
  float* o1 = part1 + (size_t)blockIdx.z * (CDIM * KPAD);
  float* o2 = part2 + (size_t)blockIdx.z * (CDIM * KPAD);
#pragma unroll
  for (int m = 0; m < 8; ++m) {
    const int c = c0 + tc * 8 + m;
    const int k = k0 + tk * 4;
    *(float4*)&o1[(size_t)c * KPAD + k] = *(const float4*)acc1[m];
    *(float4*)&o2[(size_t)c * KPAD + k] = *(const float4*)acc2[m];
  }
}

__global__ __launch_bounds__(256) void reduce_kernel(
    const float* __restrict__ part1, const float* __restrict__ part2,
    double* __restrict__ bsum, int split) {
  const int tid = threadIdx.x;
  double s = 0.0;
  for (int r = 0; r < 4; ++r) {
    const size_t idx = (size_t)blockIdx.x * 1024 + (size_t)r * 256 + tid;
    double m1 = 0.0, m2 = 0.0;
    for (int zz = 0; zz < split; ++zz) {
      m1 += (double)part1[(size_t)zz * (CDIM * KPAD) + idx];
      m2 += (double)part2[(size_t)zz * (CDIM * KPAD) + idx];
    }
    s += m1 * m2;
  }
  __shared__ double red[256];
  red[tid] = s;
  __syncthreads();
  for (int off = 128; off; off >>= 1) {
    if (tid < off) red[tid] += red[tid + off];
    __syncthreads();
  }
  if (tid == 0) bsum[blockIdx.x] = red[0];
}

// ---------------------------------------------------------------------------
// K4: final scalar.  result = -(S_all - S_diag) / (N^2 - N)
// ---------------------------------------------------------------------------
__global__ __launch_bounds__(256) void final_kernel(
    const double* __restrict__ bsum, const float* __restrict__ diag,
    float* __restrict__ out, int nb) {
  const int tid = threadIdx.x;
  double s = 0.0;
  for (int i = tid; i < nb; i += 256) s += bsum[i];
  double d = 0.0;
  for (int i = tid; i < NROWS; i += 256) d += (double)diag[i];
  __shared__ double red[256];
  red[tid] = s;
  __syncthreads();
  for (int off = 128; off; off >>= 1) {
    if (tid < off) red[tid] += red[tid + off];
    __syncthreads();
  }
  double s_all = red[0];
  __syncthreads();
  red[tid] = d;
  __syncthreads();
  for (int off = 128; off; off >>= 1) {
    if (tid < off) red[tid] += red[tid + off];
    __syncthreads();
  }
  if (tid == 0) {
    const double s_diag = red[0];
    const double sel_sum = -(s_all - s_diag);
    const double cnt = (double)NROWS * (double)NROWS - (double)NROWS;
    out[0] = (float)(sel_sum / cnt);
  }
}

extern "C" void kernel_launch(void* const* d_in, const int* in_sizes, int n_in,
                              void* d_out, int out_size, void* d_ws, size_t ws_size,
                              hipStream_t stream) {
  const float* p = (const float*)d_in[0];
  const float* z = (const float*)d_in[1];
  const float* t = (const float*)d_in[2];
  float* out = (float*)d_out;
  char* ws = (char*)d_ws;

  float* sa = (float*)ws;
  float* sb = sa + NROWS;
  float* st = sb + NROWS;
  float* diag = st + NROWS;
  const size_t statsB = (size_t)4 * NROWS * sizeof(float);  // 128 KiB

  const size_t planeA = (size_t)2 * 256 * 8 * 1024;   // 4 MiB
  const size_t planeU = (size_t)8 * 256 * 8 * 1024;   // 16 MiB
  const size_t chunkH = (size_t)CDIM * KPAD * 2;      // 512 KiB fp16 partial
  const size_t chunkF = (size_t)CDIM * KPAD * 4;      // 1 MiB fp32 partial

  int split = 16;
  while (split > 4 &&
         statsB + 4 * planeA + 2 * planeU + (size_t)split * 2 * chunkH + 8192 > ws_size)
    split >>= 1;
  const bool use_mfma =
      statsB + 4 * planeA + 2 * planeU + (size_t)split * 2 * chunkH + 8192 <= ws_size;

  if (use_mfma) {
    char* base = ws + statsB;
    unsigned short* gAhi = (unsigned short*)(base);
    unsigned short* gAlo = (unsigned short*)(base + planeA);
    unsigned short* gBhi = (unsigned short*)(base + 2 * planeA);
    unsigned short* gBlo = (unsigned short*)(base + 3 * planeA);
    unsigned short* gUhi = (unsigned short*)(base + 4 * planeA);
    unsigned short* gUlo = (unsigned short*)(base + 4 * planeA + planeU);
    f16* part1 = (f16*)(base + 4 * planeA + 2 * planeU);
    f16* part2 = part1 + (size_t)split * (CDIM * KPAD);
    double* bsum = (double*)(part2 + (size_t)split * (CDIM * KPAD));
    const int steps = (NROWS / split) / 32;
    const int nblocks = 16 * split;             // (2 ct x 8 kt) x split
    const int swz = (split % 8 == 0) ? 1 : 0;   // XCD-cluster decode valid

    hipLaunchKernelGGL(prep_kernel, dim3(1024), dim3(256), 0, stream,
                       p, z, t, gAhi, gAlo, gBhi, gBlo, gUhi, gUlo, diag);
    hipLaunchKernelGGL(mfma_gemm_kernel, dim3(nblocks), dim3(512), 0, stream,
                       gAhi, gAlo, gBhi, gBlo, gUhi, gUlo, part1, part2,
                       steps, split, swz);
    hipLaunchKernelGGL(reduce_h_kernel, dim3(256), dim3(256), 0, stream,
                       part1, part2, bsum, split);
    hipLaunchKernelGGL(final_kernel, dim3(1), dim3(256), 0, stream,
                       bsum, diag, out, 256);
  } else {
    int osplit = 16;
    while (osplit > 1 &&
           statsB + (size_t)osplit * chunkF * 2 + 8192 > ws_size)
      osplit >>= 1;
    float* part1 = (float*)(ws + statsB);
    float* part2 = part1 + (size_t)osplit * (CDIM * KPAD);
    double* bsum = (double*)(part2 + (size_t)osplit * (CDIM * KPAD));
    hipLaunchKernelGGL(rowstats_kernel, dim3(NROWS), dim3(256), 0, stream,
                       p, z, t, sa, sb, st, diag);
    hipLaunchKernelGGL(fp32_gemm_kernel, dim3(CDIM / BC, KPAD / BK, osplit),
                       dim3(256), 0, stream,
                       p, z, t, sa, sb, st, part1, part2, NROWS / osplit);
    hipLaunchKernelGGL(reduce_kernel, dim3(256), dim3(256), 0, stream,
                       part1, part2, bsum, osplit);
    hipLaunchKernelGGL(final_kernel, dim3(1), dim3(256), 0, stream,
                       bsum, diag, out, 256);
  }
}